// Round 8
// baseline (270.926 us; speedup 1.0000x reference)
//
#include <hip/hip_runtime.h>

#define N_NODES 50000
#define D 128
#define E_EDGES 800000
#define EPS 1e-5f
#define NB 196   // ceil(N_NODES/256)

typedef __attribute__((ext_vector_type(8))) short bf16x8;
typedef __attribute__((ext_vector_type(4))) float f32x4;

static __device__ __forceinline__ unsigned short f2bf(float f) {
    unsigned u = __float_as_uint(f);
    u = (u + 0x7fffu + ((u >> 16) & 1u)) >> 16;   // RNE
    return (unsigned short)u;
}
static __device__ __forceinline__ float bf2f(unsigned short h) {
    return __uint_as_float((unsigned)h << 16);
}

// ---- Kernel 1: fused LayerNorm + H = LN @ W (bf16 MFMA) + zero counts ----
// Block: 256 thr = 4 waves, 64 rows. A-tile bf16 in swizzled LDS (16 KB).
// W fragments loaded straight from global (L2-hot) into VGPRs; no W LDS.
__global__ __launch_bounds__(256) void lngemm_kernel(const float* __restrict__ x,
                                                     const float* __restrict__ W,
                                                     float* __restrict__ ln,
                                                     unsigned short* __restrict__ Hb,
                                                     int* __restrict__ counts) {
    __shared__ __align__(16) unsigned char A_lds[64 * 256];   // 64 rows x 128 bf16, swizzled
    int tid  = threadIdx.x;
    int wv   = tid >> 6;
    int lane = tid & 63;
    int row0 = blockIdx.x * 64;

    // fused zero of the degree histogram (782*256 = 200K covers 50K)
    int zi = blockIdx.x * 256 + tid;
    if (zi < N_NODES) counts[zi] = 0;

    // --- W fragments -> VGPRs: wave owns col-tiles {2wv, 2wv+1}, kb = 0..3 ---
    bf16x8 bfrag[2][4];
    {
        int colb = (lane & 15);
        int kr   = (lane >> 4) * 8;
        #pragma unroll
        for (int ci = 0; ci < 2; ++ci) {
            int col = (wv * 2 + ci) * 16 + colb;
            #pragma unroll
            for (int kb = 0; kb < 4; ++kb) {
                #pragma unroll
                for (int j = 0; j < 8; ++j) {
                    float wvf = W[(size_t)(kb * 32 + kr + j) * D + col];
                    bfrag[ci][kb][j] = (short)f2bf(wvf);
                }
            }
        }
    }

    // --- LayerNorm: wave wv handles rows row0 + wv*16 .. +15 ---
    #pragma unroll
    for (int i = 0; i < 16; ++i) {
        int lr  = wv * 16 + i;
        int row = row0 + lr;
        if (row < N_NODES) {
            float2 v = ((const float2*)(x + (size_t)row * D))[lane];
            float s = v.x + v.y;
            #pragma unroll
            for (int off = 32; off > 0; off >>= 1) s += __shfl_xor(s, off);
            float mu = s * (1.0f / D);
            float dx = v.x - mu, dy = v.y - mu;
            float vs = dx * dx + dy * dy;
            #pragma unroll
            for (int off = 32; off > 0; off >>= 1) vs += __shfl_xor(vs, off);
            float rstd = rsqrtf(vs * (1.0f / D) + EPS);
            float2 o; o.x = dx * rstd; o.y = dy * rstd;
            ((float2*)(ln + (size_t)row * D))[lane] = o;
            unsigned pk = (unsigned)f2bf(o.x) | ((unsigned)f2bf(o.y) << 16);
            // swizzled store: byte = lr*256 + (4*lane ^ ((lr&7)<<4))
            *(unsigned*)(A_lds + lr * 256 + ((4 * lane) ^ ((lr & 7) << 4))) = pk;
        }
    }
    __syncthreads();

    // --- MFMA: 4 row-tiles x 2 col-tiles x 4 k-blocks per wave ---
    f32x4 acc[4][2] = {};
    #pragma unroll
    for (int kb = 0; kb < 4; ++kb) {
        #pragma unroll
        for (int rt = 0; rt < 4; ++rt) {
            int lr = rt * 16 + (lane & 15);
            bf16x8 af = *(const bf16x8*)(A_lds + lr * 256 +
                          ((kb * 64 + (lane >> 4) * 16) ^ ((lr & 7) << 4)));
            acc[rt][0] = __builtin_amdgcn_mfma_f32_16x16x32_bf16(af, bfrag[0][kb], acc[rt][0], 0, 0, 0);
            acc[rt][1] = __builtin_amdgcn_mfma_f32_16x16x32_bf16(af, bfrag[1][kb], acc[rt][1], 0, 0, 0);
        }
    }

    // --- epilogue: H bf16.  C/D layout: col = lane&15, row = (lane>>4)*4 + reg ---
    #pragma unroll
    for (int rt = 0; rt < 4; ++rt) {
        #pragma unroll
        for (int ci = 0; ci < 2; ++ci) {
            int col   = (wv * 2 + ci) * 16 + (lane & 15);
            int rbase = row0 + rt * 16 + ((lane >> 4) << 2);
            #pragma unroll
            for (int reg = 0; reg < 4; ++reg) {
                int r = rbase + reg;
                if (r < N_NODES)
                    Hb[(size_t)r * D + col] = f2bf(acc[rt][ci][reg]);
            }
        }
    }
}

// ---------------- Kernel 2: histogram of dst ----------------
__global__ __launch_bounds__(256) void hist_kernel(const int* __restrict__ ei,
                                                   int* __restrict__ counts) {
    int e = blockIdx.x * 256 + threadIdx.x;
    if (e < E_EDGES) atomicAdd(&counts[ei[E_EDGES + e]], 1);
}

// ---------------- Kernel 3a: per-block sums of counts ----------------
__global__ __launch_bounds__(256) void blocksum_kernel(const int* __restrict__ counts,
                                                       int* __restrict__ partial) {
    __shared__ int red[256];
    int i = blockIdx.x * 256 + threadIdx.x;
    red[threadIdx.x] = (i < N_NODES) ? counts[i] : 0;
    __syncthreads();
    #pragma unroll
    for (int off = 128; off > 0; off >>= 1) {
        if (threadIdx.x < off) red[threadIdx.x] += red[threadIdx.x + off];
        __syncthreads();
    }
    if (threadIdx.x == 0) partial[blockIdx.x] = red[0];
}

// ---------------- Kernel 3b: exclusive scan of the 196 partials (1 block) --------
__global__ __launch_bounds__(256) void scanpartial_kernel(int* __restrict__ partial) {
    __shared__ int s[256];
    int t = threadIdx.x;
    s[t] = (t < NB) ? partial[t] : 0;
    __syncthreads();
    #pragma unroll
    for (int off = 1; off < 256; off <<= 1) {
        int u = (t >= off) ? s[t - off] : 0;
        __syncthreads();
        s[t] += u;
        __syncthreads();
    }
    if (t < NB) partial[t] = (t == 0) ? 0 : s[t - 1];
}

// ---------------- Kernel 3c: block-local scan + partial offset -> row_start ------
__global__ __launch_bounds__(256) void writeoffs_kernel(const int* __restrict__ counts,
                                                        const int* __restrict__ partial,
                                                        int* __restrict__ row_start,
                                                        int* __restrict__ cursor) {
    __shared__ int s[256];
    int t = threadIdx.x;
    int i = blockIdx.x * 256 + t;
    s[t] = (i < N_NODES) ? counts[i] : 0;
    __syncthreads();
    #pragma unroll
    for (int off = 1; off < 256; off <<= 1) {
        int u = (t >= off) ? s[t - off] : 0;
        __syncthreads();
        s[t] += u;
        __syncthreads();
    }
    int excl = partial[blockIdx.x] + ((t == 0) ? 0 : s[t - 1]);
    if (i < N_NODES) { row_start[i] = excl; cursor[i] = excl; }
    if (i == N_NODES - 1) row_start[N_NODES] = E_EDGES;
}

// ------- Kernel 4: reorder edges into CSR order, packed 4B (src<<15 | bf16w) -----
__global__ __launch_bounds__(256) void reorder_kernel(const int* __restrict__ ei,
                                                      const float* __restrict__ ew,
                                                      int* __restrict__ cursor,
                                                      unsigned* __restrict__ swp) {
    int e = blockIdx.x * 256 + threadIdx.x;
    if (e >= E_EDGES) return;
    int dst = ei[E_EDGES + e];
    int pos = atomicAdd(&cursor[dst], 1);
    unsigned pk = ((unsigned)ei[e] << 15) | ((unsigned)f2bf(ew[e]) & 0x7fffu);
    swp[pos] = pk;
}

// ------- Kernel 5: gather-aggregate (bf16 H) + fused bias/dropout/residual -------
// Half-wave (32 lanes) per node; lane covers 4 of D=128 (ushort4 = 8B).
__global__ __launch_bounds__(256) void gather_kernel(const int* __restrict__ row_start,
                                                     const unsigned* __restrict__ swp,
                                                     const unsigned short* __restrict__ Hb,
                                                     const float* __restrict__ b,
                                                     const float* __restrict__ mask,
                                                     const float* __restrict__ ln,
                                                     float* __restrict__ out) {
    int wave = threadIdx.x >> 6;
    int lane = threadIdx.x & 63;
    int half = lane >> 5;
    int l    = lane & 31;
    int node = blockIdx.x * 8 + wave * 2 + half;   // 6250 * 8 = 50000 exact
    int beg = row_start[node], end = row_start[node + 1];
    float4 acc = make_float4(0.f, 0.f, 0.f, 0.f);
    int e = beg;
    for (; e + 8 <= end; e += 8) {                 // 8-edge MLP
        unsigned p[8]; ushort4 hv[8];
        #pragma unroll
        for (int j = 0; j < 8; ++j) p[j] = swp[e + j];
        #pragma unroll
        for (int j = 0; j < 8; ++j)
            hv[j] = *(const ushort4*)(Hb + (size_t)(p[j] >> 15) * D + l * 4);
        #pragma unroll
        for (int j = 0; j < 8; ++j) {
            float w = __uint_as_float((p[j] & 0x7fffu) << 16);
            acc.x = fmaf(w, bf2f(hv[j].x), acc.x);
            acc.y = fmaf(w, bf2f(hv[j].y), acc.y);
            acc.z = fmaf(w, bf2f(hv[j].z), acc.z);
            acc.w = fmaf(w, bf2f(hv[j].w), acc.w);
        }
    }
    for (; e < end; ++e) {
        unsigned p0 = swp[e];
        ushort4 h0 = *(const ushort4*)(Hb + (size_t)(p0 >> 15) * D + l * 4);
        float w = __uint_as_float((p0 & 0x7fffu) << 16);
        acc.x = fmaf(w, bf2f(h0.x), acc.x);
        acc.y = fmaf(w, bf2f(h0.y), acc.y);
        acc.z = fmaf(w, bf2f(h0.z), acc.z);
        acc.w = fmaf(w, bf2f(h0.w), acc.w);
    }
    size_t o4 = (size_t)node * 32 + l;
    float4 bv = ((const float4*)b)[l];
    float4 mv = ((const float4*)mask)[o4];
    float4 lv = ((const float4*)ln)[o4];
    float4 r;
    r.x = (acc.x + bv.x) * mv.x - lv.x;
    r.y = (acc.y + bv.y) * mv.y - lv.y;
    r.z = (acc.z + bv.z) * mv.z - lv.z;
    r.w = (acc.w + bv.w) * mv.w - lv.w;
    ((float4*)out)[o4] = r;
}

extern "C" void kernel_launch(void* const* d_in, const int* in_sizes, int n_in,
                              void* d_out, int out_size, void* d_ws, size_t ws_size,
                              hipStream_t stream) {
    const float* node_inputs = (const float*)d_in[0];
    const int*   edge_index  = (const int*)d_in[1];
    const float* edge_w      = (const float*)d_in[2];
    const float* W           = (const float*)d_in[3];
    const float* b           = (const float*)d_in[4];
    const float* mask        = (const float*)d_in[5];
    float* out = (float*)d_out;

    const size_t ND = (size_t)N_NODES * D;
    const int NP = 50004;                             // padded N+1, even
    float*          ln        = (float*)d_ws;         // ND f32
    unsigned short* Hb        = (unsigned short*)(ln + ND);   // ND bf16
    int*            row_start = (int*)(Hb + ND);      // NP ints
    int*            cursor    = row_start + NP;       // NP ints
    int*            counts    = cursor + NP;          // NP ints
    unsigned*       swp       = (unsigned*)(counts + NP);  // E u32
    int*            partial   = (int*)(swp + E_EDGES);     // NB ints

    lngemm_kernel<<<(N_NODES + 63) / 64, 256, 0, stream>>>(node_inputs, W, ln, Hb, counts);
    hist_kernel<<<(E_EDGES + 255) / 256, 256, 0, stream>>>(edge_index, counts);
    blocksum_kernel<<<NB, 256, 0, stream>>>(counts, partial);
    scanpartial_kernel<<<1, 256, 0, stream>>>(partial);
    writeoffs_kernel<<<NB, 256, 0, stream>>>(counts, partial, row_start, cursor);
    reorder_kernel<<<(E_EDGES + 255) / 256, 256, 0, stream>>>(edge_index, edge_w,
                                                              cursor, swp);
    gather_kernel<<<N_NODES / 8, 256, 0, stream>>>(row_start, swp, Hb,
                                                   b, mask, ln, out);
}

// Round 9
// 227.590 us; speedup vs baseline: 1.1904x; 1.1904x over previous
//
#include <hip/hip_runtime.h>

#define N_NODES 50000
#define D 128
#define E_EDGES 800000
#define EPS 1e-5f

#define BKT_SHIFT 9
#define BNODES 512                      // nodes per bucket
#define NBKT 98                         // ceil(50000/512)
#define P1_EPB 4096                     // edges per phase-1 block
#define P1_BLOCKS 196                   // ceil(800000/4096)

typedef __attribute__((ext_vector_type(8))) short bf16x8;
typedef __attribute__((ext_vector_type(4))) float f32x4;

static __device__ __forceinline__ unsigned short f2bf(float f) {
    unsigned u = __float_as_uint(f);
    u = (u + 0x7fffu + ((u >> 16) & 1u)) >> 16;   // RNE
    return (unsigned short)u;
}
static __device__ __forceinline__ float bf2f(unsigned short h) {
    return __uint_as_float((unsigned)h << 16);
}

// ---- Kernel 1: fused LayerNorm + H = LN @ W (bf16 MFMA) + zero bucket counters ----
__global__ __launch_bounds__(256) void lngemm_kernel(const float* __restrict__ x,
                                                     const float* __restrict__ W,
                                                     float* __restrict__ ln,
                                                     unsigned short* __restrict__ Hb,
                                                     int* __restrict__ bucket_cnt) {
    __shared__ __align__(16) unsigned char A_lds[64 * 256];   // 64 rows x 128 bf16, swizzled
    int tid  = threadIdx.x;
    int wv   = tid >> 6;
    int lane = tid & 63;
    int row0 = blockIdx.x * 64;

    if (blockIdx.x == 0 && tid < NBKT) bucket_cnt[tid] = 0;   // A runs after us

    // --- W fragments -> VGPRs: wave owns col-tiles {2wv, 2wv+1}, kb = 0..3 ---
    bf16x8 bfrag[2][4];
    {
        int colb = (lane & 15);
        int kr   = (lane >> 4) * 8;
        #pragma unroll
        for (int ci = 0; ci < 2; ++ci) {
            int col = (wv * 2 + ci) * 16 + colb;
            #pragma unroll
            for (int kb = 0; kb < 4; ++kb) {
                #pragma unroll
                for (int j = 0; j < 8; ++j) {
                    float wvf = W[(size_t)(kb * 32 + kr + j) * D + col];
                    bfrag[ci][kb][j] = (short)f2bf(wvf);
                }
            }
        }
    }

    // --- LayerNorm: wave wv handles rows row0 + wv*16 .. +15 ---
    #pragma unroll
    for (int i = 0; i < 16; ++i) {
        int lr  = wv * 16 + i;
        int row = row0 + lr;
        if (row < N_NODES) {
            float2 v = ((const float2*)(x + (size_t)row * D))[lane];
            float s = v.x + v.y;
            #pragma unroll
            for (int off = 32; off > 0; off >>= 1) s += __shfl_xor(s, off);
            float mu = s * (1.0f / D);
            float dx = v.x - mu, dy = v.y - mu;
            float vs = dx * dx + dy * dy;
            #pragma unroll
            for (int off = 32; off > 0; off >>= 1) vs += __shfl_xor(vs, off);
            float rstd = rsqrtf(vs * (1.0f / D) + EPS);
            float2 o; o.x = dx * rstd; o.y = dy * rstd;
            ((float2*)(ln + (size_t)row * D))[lane] = o;
            unsigned pk = (unsigned)f2bf(o.x) | ((unsigned)f2bf(o.y) << 16);
            *(unsigned*)(A_lds + lr * 256 + ((4 * lane) ^ ((lr & 7) << 4))) = pk;
        }
    }
    __syncthreads();

    // --- MFMA: 4 row-tiles x 2 col-tiles x 4 k-blocks per wave ---
    f32x4 acc[4][2] = {};
    #pragma unroll
    for (int kb = 0; kb < 4; ++kb) {
        #pragma unroll
        for (int rt = 0; rt < 4; ++rt) {
            int lr = rt * 16 + (lane & 15);
            bf16x8 af = *(const bf16x8*)(A_lds + lr * 256 +
                          ((kb * 64 + (lane >> 4) * 16) ^ ((lr & 7) << 4)));
            acc[rt][0] = __builtin_amdgcn_mfma_f32_16x16x32_bf16(af, bfrag[0][kb], acc[rt][0], 0, 0, 0);
            acc[rt][1] = __builtin_amdgcn_mfma_f32_16x16x32_bf16(af, bfrag[1][kb], acc[rt][1], 0, 0, 0);
        }
    }

    // --- epilogue: H bf16.  C/D layout: col = lane&15, row = (lane>>4)*4 + reg ---
    #pragma unroll
    for (int rt = 0; rt < 4; ++rt) {
        #pragma unroll
        for (int ci = 0; ci < 2; ++ci) {
            int col   = (wv * 2 + ci) * 16 + (lane & 15);
            int rbase = row0 + rt * 16 + ((lane >> 4) << 2);
            #pragma unroll
            for (int reg = 0; reg < 4; ++reg) {
                int r = rbase + reg;
                if (r < N_NODES)
                    Hb[(size_t)r * D + col] = f2bf(acc[rt][ci][reg]);
            }
        }
    }
}

// ---------------- Kernel A: per-bucket edge counts (LDS hist -> 98 atomics/blk) ----
__global__ __launch_bounds__(256) void bucket_hist(const int* __restrict__ ei,
                                                   int* __restrict__ bucket_cnt) {
    __shared__ int h[NBKT];
    int t = threadIdx.x;
    int base = blockIdx.x * P1_EPB;
    for (int i = t; i < NBKT; i += 256) h[i] = 0;
    __syncthreads();
    int cnt = E_EDGES - base; if (cnt > P1_EPB) cnt = P1_EPB;
    for (int i = t; i < cnt; i += 256)
        atomicAdd(&h[ei[E_EDGES + base + i] >> BKT_SHIFT], 1);
    __syncthreads();
    if (t < NBKT && h[t]) atomicAdd(&bucket_cnt[t], h[t]);
}

// ---------------- Kernel B: scan 98 bucket totals (1 block, 128 thr) -------------
__global__ __launch_bounds__(128) void bucket_scan(const int* __restrict__ bucket_cnt,
                                                   int* __restrict__ bucket_base,
                                                   int* __restrict__ bcursor,
                                                   int* __restrict__ row_start) {
    __shared__ int s[128];
    int t = threadIdx.x;
    s[t] = (t < NBKT) ? bucket_cnt[t] : 0;
    __syncthreads();
    #pragma unroll
    for (int off = 1; off < 128; off <<= 1) {
        int u = (t >= off) ? s[t - off] : 0;
        __syncthreads();
        s[t] += u;
        __syncthreads();
    }
    if (t < NBKT) {
        int excl = s[t] - bucket_cnt[t];
        bucket_base[t] = excl;
        bcursor[t]     = excl;
    }
    if (t == 0) { bucket_base[NBKT] = E_EDGES; row_start[N_NODES] = E_EDGES; }
}

// ---- Kernel C: phase-1 partition — per-block run reservation, scatter int2 ------
// Each run (~42 edges x 8B) is written by exactly one block => L2 write-combines.
__global__ __launch_bounds__(256) void phase1_kernel(const int* __restrict__ ei,
                                                     const float* __restrict__ ew,
                                                     int* __restrict__ bcursor,
                                                     int2* __restrict__ bstage) {
    __shared__ int h[NBKT], grun[NBKT], lcur[NBKT];
    int t = threadIdx.x;
    int base = blockIdx.x * P1_EPB;
    for (int i = t; i < NBKT; i += 256) h[i] = 0;
    __syncthreads();
    int cnt = E_EDGES - base; if (cnt > P1_EPB) cnt = P1_EPB;
    for (int i = t; i < cnt; i += 256)
        atomicAdd(&h[ei[E_EDGES + base + i] >> BKT_SHIFT], 1);
    __syncthreads();
    if (t < NBKT) {
        grun[t] = h[t] ? atomicAdd(&bcursor[t], h[t]) : 0;
        lcur[t] = 0;
    }
    __syncthreads();
    for (int i = t; i < cnt; i += 256) {
        int e   = base + i;
        int dst = ei[E_EDGES + e];
        int bkt = dst >> BKT_SHIFT;
        int r   = atomicAdd(&lcur[bkt], 1);
        int2 p;
        p.x = dst;
        p.y = (int)(((unsigned)ei[e] << 15) | ((unsigned)f2bf(ew[e]) & 0x7fffu));
        bstage[grun[bkt] + r] = p;
    }
}

// ---- Kernel D: phase-2 — per-bucket counting sort into final CSR + row_start ----
// One block per bucket; its 32KB swp region is written by one block/XCD.
__global__ __launch_bounds__(256) void phase2_kernel(const int2* __restrict__ bstage,
                                                     const int* __restrict__ bucket_base,
                                                     int* __restrict__ row_start,
                                                     unsigned* __restrict__ swp) {
    __shared__ int cnt[BNODES], ncur[BNODES];
    int b = blockIdx.x, t = threadIdx.x;
    int nbase = b << BKT_SHIFT;
    int ebeg = bucket_base[b], eend = bucket_base[b + 1];
    for (int i = t; i < BNODES; i += 256) cnt[i] = 0;
    __syncthreads();
    for (int i = ebeg + t; i < eend; i += 256)
        atomicAdd(&cnt[bstage[i].x - nbase], 1);
    __syncthreads();
    // inclusive Hillis-Steele over cnt[512], 2 elems/thread
    #pragma unroll
    for (int off = 1; off < BNODES; off <<= 1) {
        int a0 = (t >= off) ? cnt[t - off] : 0;
        int i1 = t + 256;
        int a1 = (i1 >= off) ? cnt[i1 - off] : 0;
        __syncthreads();
        cnt[t] += a0; cnt[i1] += a1;
        __syncthreads();
    }
    int nc = N_NODES - nbase; if (nc > BNODES) nc = BNODES;
    for (int i = t; i < nc; i += 256) {
        int ab = ebeg + ((i == 0) ? 0 : cnt[i - 1]);   // exclusive prefix
        row_start[nbase + i] = ab;
        ncur[i] = ab;
    }
    __syncthreads();
    for (int i = ebeg + t; i < eend; i += 256) {
        int2 p = bstage[i];
        int pos = atomicAdd(&ncur[p.x - nbase], 1);
        swp[pos] = (unsigned)p.y;
    }
}

// ------- Kernel 5: gather-aggregate (bf16 H) + fused bias/dropout/residual -------
__global__ __launch_bounds__(256) void gather_kernel(const int* __restrict__ row_start,
                                                     const unsigned* __restrict__ swp,
                                                     const unsigned short* __restrict__ Hb,
                                                     const float* __restrict__ b,
                                                     const float* __restrict__ mask,
                                                     const float* __restrict__ ln,
                                                     float* __restrict__ out) {
    int wave = threadIdx.x >> 6;
    int lane = threadIdx.x & 63;
    int half = lane >> 5;
    int l    = lane & 31;
    int node = blockIdx.x * 8 + wave * 2 + half;   // 6250 * 8 = 50000 exact
    int beg = row_start[node], end = row_start[node + 1];
    float4 acc = make_float4(0.f, 0.f, 0.f, 0.f);
    int e = beg;
    for (; e + 8 <= end; e += 8) {                 // 8-edge MLP
        unsigned p[8]; ushort4 hv[8];
        #pragma unroll
        for (int j = 0; j < 8; ++j) p[j] = swp[e + j];
        #pragma unroll
        for (int j = 0; j < 8; ++j)
            hv[j] = *(const ushort4*)(Hb + (size_t)(p[j] >> 15) * D + l * 4);
        #pragma unroll
        for (int j = 0; j < 8; ++j) {
            float w = __uint_as_float((p[j] & 0x7fffu) << 16);
            acc.x = fmaf(w, bf2f(hv[j].x), acc.x);
            acc.y = fmaf(w, bf2f(hv[j].y), acc.y);
            acc.z = fmaf(w, bf2f(hv[j].z), acc.z);
            acc.w = fmaf(w, bf2f(hv[j].w), acc.w);
        }
    }
    for (; e < end; ++e) {
        unsigned p0 = swp[e];
        ushort4 h0 = *(const ushort4*)(Hb + (size_t)(p0 >> 15) * D + l * 4);
        float w = __uint_as_float((p0 & 0x7fffu) << 16);
        acc.x = fmaf(w, bf2f(h0.x), acc.x);
        acc.y = fmaf(w, bf2f(h0.y), acc.y);
        acc.z = fmaf(w, bf2f(h0.z), acc.z);
        acc.w = fmaf(w, bf2f(h0.w), acc.w);
    }
    size_t o4 = (size_t)node * 32 + l;
    float4 bv = ((const float4*)b)[l];
    float4 mv = ((const float4*)mask)[o4];
    float4 lv = ((const float4*)ln)[o4];
    float4 r;
    r.x = (acc.x + bv.x) * mv.x - lv.x;
    r.y = (acc.y + bv.y) * mv.y - lv.y;
    r.z = (acc.z + bv.z) * mv.z - lv.z;
    r.w = (acc.w + bv.w) * mv.w - lv.w;
    ((float4*)out)[o4] = r;
}

extern "C" void kernel_launch(void* const* d_in, const int* in_sizes, int n_in,
                              void* d_out, int out_size, void* d_ws, size_t ws_size,
                              hipStream_t stream) {
    const float* node_inputs = (const float*)d_in[0];
    const int*   edge_index  = (const int*)d_in[1];
    const float* edge_w      = (const float*)d_in[2];
    const float* W           = (const float*)d_in[3];
    const float* b           = (const float*)d_in[4];
    const float* mask        = (const float*)d_in[5];
    float* out = (float*)d_out;

    const size_t ND = (size_t)N_NODES * D;
    float*          ln          = (float*)d_ws;                    // ND f32 (25.6 MB)
    unsigned short* Hb          = (unsigned short*)(ln + ND);      // ND bf16 (12.8 MB)
    int2*           bstage      = (int2*)(Hb + ND);                // E int2 (6.4 MB, 8B-aligned)
    unsigned*       swp         = (unsigned*)(bstage + E_EDGES);   // E u32 (3.2 MB)
    int*            row_start   = (int*)(swp + E_EDGES);           // N+1 (pad 50004)
    int*            bucket_cnt  = row_start + 50004;               // NBKT
    int*            bucket_base = bucket_cnt + NBKT;               // NBKT+1
    int*            bcursor     = bucket_base + NBKT + 2;          // NBKT

    lngemm_kernel<<<(N_NODES + 63) / 64, 256, 0, stream>>>(node_inputs, W, ln, Hb, bucket_cnt);
    bucket_hist<<<P1_BLOCKS, 256, 0, stream>>>(edge_index, bucket_cnt);
    bucket_scan<<<1, 128, 0, stream>>>(bucket_cnt, bucket_base, bcursor, row_start);
    phase1_kernel<<<P1_BLOCKS, 256, 0, stream>>>(edge_index, edge_w, bcursor, bstage);
    phase2_kernel<<<NBKT, 256, 0, stream>>>(bstage, bucket_base, row_start, swp);
    gather_kernel<<<N_NODES / 8, 256, 0, stream>>>(row_start, swp, Hb,
                                                   b, mask, ln, out);
}

// Round 10
// 199.452 us; speedup vs baseline: 1.3584x; 1.1411x over previous
//
#include <hip/hip_runtime.h>

#define N_NODES 50000
#define D 128
#define E_EDGES 800000
#define EPS 1e-5f

#define BKT_SHIFT 9
#define BNODES 512                      // nodes per bucket
#define NBKT 98                         // ceil(50000/512)
#define BCAP 10240                      // slots per bucket (mean 8163, >20 sigma pad)
#define P1_EPB 4096                     // edges per phase-1 block
#define P1_BLOCKS 196                   // ceil(800000/4096)

typedef __attribute__((ext_vector_type(8))) short bf16x8;
typedef __attribute__((ext_vector_type(4))) float f32x4;
typedef __attribute__((ext_vector_type(2))) unsigned u32x2;

static __device__ __forceinline__ unsigned short f2bf(float f) {
    unsigned u = __float_as_uint(f);
    u = (u + 0x7fffu + ((u >> 16) & 1u)) >> 16;   // RNE
    return (unsigned short)u;
}
static __device__ __forceinline__ float bf2f(unsigned short h) {
    return __uint_as_float((unsigned)h << 16);
}

// ---- Kernel 0: W -> Wt[col][k] bf16 (fragment-contiguous) + zero bucket counters --
__global__ __launch_bounds__(256) void wprep_kernel(const float* __restrict__ W,
                                                    unsigned short* __restrict__ Wt,
                                                    int* __restrict__ bcnt) {
    int idx = blockIdx.x * 256 + threadIdx.x;       // 64 blocks * 256 = 16384 exact
    if (blockIdx.x == 0 && threadIdx.x < NBKT) bcnt[threadIdx.x] = 0;
    int k = idx >> 7, c = idx & 127;
    Wt[c * 128 + k] = f2bf(W[idx]);
}

// ---- Kernel 1: fused LayerNorm (bf16 out) + H = LN @ W (bf16 MFMA) ----
// 256 thr = 4 waves, 64 rows. B-fragments: one 16B load each from Wt (L2-hot).
__global__ __launch_bounds__(256, 4) void lngemm_kernel(const float* __restrict__ x,
                                                        const unsigned short* __restrict__ Wt,
                                                        unsigned short* __restrict__ lnb,
                                                        unsigned short* __restrict__ Hb) {
    __shared__ __align__(16) unsigned char A_lds[64 * 256];   // 64 rows x 128 bf16, swizzled
    int tid  = threadIdx.x;
    int wv   = tid >> 6;
    int lane = tid & 63;
    int row0 = blockIdx.x * 64;

    // --- B fragments: wave owns col-tiles {2wv, 2wv+1}; 8 x dwordx4 loads total ---
    bf16x8 bfrag[2][4];
    #pragma unroll
    for (int ci = 0; ci < 2; ++ci) {
        int col = (wv * 2 + ci) * 16 + (lane & 15);
        #pragma unroll
        for (int kb = 0; kb < 4; ++kb)
            bfrag[ci][kb] = *(const bf16x8*)(Wt + col * 128 + kb * 32 + (lane >> 4) * 8);
    }

    // --- LN: prefetch all 16 rows (independent loads), then reduce ---
    float2 xv[16];
    #pragma unroll
    for (int i = 0; i < 16; ++i) {
        int row = row0 + wv * 16 + i;
        xv[i] = (row < N_NODES) ? ((const float2*)(x + (size_t)row * D))[lane]
                                : make_float2(0.f, 0.f);
    }
    #pragma unroll
    for (int i = 0; i < 16; ++i) {
        int lr  = wv * 16 + i;
        int row = row0 + lr;
        float2 v = xv[i];
        float s = v.x + v.y;
        #pragma unroll
        for (int off = 32; off > 0; off >>= 1) s += __shfl_xor(s, off);
        float mu = s * (1.0f / D);
        float dx = v.x - mu, dy = v.y - mu;
        float vs = dx * dx + dy * dy;
        #pragma unroll
        for (int off = 32; off > 0; off >>= 1) vs += __shfl_xor(vs, off);
        float rstd = rsqrtf(vs * (1.0f / D) + EPS);
        unsigned pk = (unsigned)f2bf(dx * rstd) | ((unsigned)f2bf(dy * rstd) << 16);
        if (row < N_NODES) ((unsigned*)lnb)[(size_t)row * 64 + lane] = pk;
        *(unsigned*)(A_lds + lr * 256 + ((4 * lane) ^ ((i & 7) << 4))) = pk;  // pad rows: zeros
    }
    __syncthreads();

    // --- MFMA: 4 row-tiles x 2 col-tiles x 4 k-blocks per wave ---
    f32x4 acc[4][2] = {};
    #pragma unroll
    for (int kb = 0; kb < 4; ++kb) {
        #pragma unroll
        for (int rt = 0; rt < 4; ++rt) {
            int lr = rt * 16 + (lane & 15);
            bf16x8 af = *(const bf16x8*)(A_lds + lr * 256 +
                          ((kb * 64 + (lane >> 4) * 16) ^ ((lr & 7) << 4)));
            acc[rt][0] = __builtin_amdgcn_mfma_f32_16x16x32_bf16(af, bfrag[0][kb], acc[rt][0], 0, 0, 0);
            acc[rt][1] = __builtin_amdgcn_mfma_f32_16x16x32_bf16(af, bfrag[1][kb], acc[rt][1], 0, 0, 0);
        }
    }

    // --- epilogue: H bf16.  C/D layout: col = lane&15, row = (lane>>4)*4 + reg ---
    #pragma unroll
    for (int rt = 0; rt < 4; ++rt) {
        #pragma unroll
        for (int ci = 0; ci < 2; ++ci) {
            int col   = (wv * 2 + ci) * 16 + (lane & 15);
            int rbase = row0 + rt * 16 + ((lane >> 4) << 2);
            #pragma unroll
            for (int reg = 0; reg < 4; ++reg) {
                int r = rbase + reg;
                if (r < N_NODES)
                    Hb[(size_t)r * D + col] = f2bf(acc[rt][ci][reg]);
            }
        }
    }
}

// ---- Kernel 2: phase-1 partition into static bucket regions -----------------
__global__ __launch_bounds__(256) void phase1_kernel(const int* __restrict__ ei,
                                                     const float* __restrict__ ew,
                                                     int* __restrict__ bcnt,
                                                     int2* __restrict__ bstage) {
    __shared__ int h[NBKT], grun[NBKT], lcur[NBKT];
    int t = threadIdx.x;
    int base = blockIdx.x * P1_EPB;
    for (int i = t; i < NBKT; i += 256) h[i] = 0;
    __syncthreads();
    int cnt = E_EDGES - base; if (cnt > P1_EPB) cnt = P1_EPB;
    for (int i = t; i < cnt; i += 256)
        atomicAdd(&h[ei[E_EDGES + base + i] >> BKT_SHIFT], 1);
    __syncthreads();
    if (t < NBKT) {
        grun[t] = h[t] ? atomicAdd(&bcnt[t], h[t]) : 0;
        lcur[t] = 0;
    }
    __syncthreads();
    for (int i = t; i < cnt; i += 256) {
        int e   = base + i;
        int dst = ei[E_EDGES + e];
        int bkt = dst >> BKT_SHIFT;
        int r   = atomicAdd(&lcur[bkt], 1);
        int2 p;
        p.x = dst;
        p.y = (int)(((unsigned)ei[e] << 15) | ((unsigned)f2bf(ew[e]) & 0x7fffu));
        bstage[(size_t)bkt * BCAP + grun[bkt] + r] = p;
    }
}

// ---- Kernel 3: phase-2 per-bucket counting sort -> swp + per-node (beg,end) -----
__global__ __launch_bounds__(256) void phase2_kernel(const int2* __restrict__ bstage,
                                                     const int* __restrict__ bcnt,
                                                     int2* __restrict__ rowse,
                                                     unsigned* __restrict__ swp) {
    __shared__ int cnt[BNODES], ncur[BNODES];
    int b = blockIdx.x, t = threadIdx.x;
    int nbase = b << BKT_SHIFT;
    int ebase = b * BCAP;
    int ecnt  = bcnt[b];
    for (int i = t; i < BNODES; i += 256) cnt[i] = 0;
    __syncthreads();
    for (int i = t; i < ecnt; i += 256)
        atomicAdd(&cnt[bstage[ebase + i].x - nbase], 1);
    __syncthreads();
    int c0a = cnt[t], c0b = cnt[t + 256];
    __syncthreads();
    // inclusive Hillis-Steele over cnt[512], 2 elems/thread
    #pragma unroll
    for (int off = 1; off < BNODES; off <<= 1) {
        int a0 = (t >= off) ? cnt[t - off] : 0;
        int i1 = t + 256;
        int a1 = (i1 >= off) ? cnt[i1 - off] : 0;
        __syncthreads();
        cnt[t] += a0; cnt[i1] += a1;
        __syncthreads();
    }
    int nc = N_NODES - nbase; if (nc > BNODES) nc = BNODES;
    {
        int i = t, incl = cnt[i], beg = ebase + incl - c0a;
        if (i < nc) { rowse[nbase + i] = make_int2(beg, ebase + incl); ncur[i] = beg; }
    }
    {
        int i = t + 256, incl = cnt[i], beg = ebase + incl - c0b;
        if (i < nc) { rowse[nbase + i] = make_int2(beg, ebase + incl); ncur[i] = beg; }
    }
    __syncthreads();
    for (int i = t; i < ecnt; i += 256) {
        int2 p = bstage[ebase + i];
        int pos = atomicAdd(&ncur[p.x - nbase], 1);
        swp[pos] = (unsigned)p.y;
    }
}

// ---- Kernel 4: gather-aggregate (bf16 H) + fused bias/dropout/residual ----------
// Half-wave (32 lanes) per node; nontemporal on all streamed traffic.
__global__ __launch_bounds__(256) void gather_kernel(const int2* __restrict__ rowse,
                                                     const unsigned* __restrict__ swp,
                                                     const unsigned short* __restrict__ Hb,
                                                     const float* __restrict__ bias,
                                                     const float* __restrict__ mask,
                                                     const unsigned short* __restrict__ lnb,
                                                     float* __restrict__ out) {
    int wave = threadIdx.x >> 6;
    int lane = threadIdx.x & 63;
    int half = lane >> 5;
    int l    = lane & 31;
    int node = blockIdx.x * 8 + wave * 2 + half;   // 6250 * 8 = 50000 exact
    int2 se  = rowse[node];
    int e = se.x, end = se.y;
    f32x4 acc = {0.f, 0.f, 0.f, 0.f};
    for (; e + 8 <= end; e += 8) {                 // 8-edge MLP
        unsigned p[8]; ushort4 hv[8];
        #pragma unroll
        for (int j = 0; j < 8; ++j) p[j] = __builtin_nontemporal_load(swp + e + j);
        #pragma unroll
        for (int j = 0; j < 8; ++j)
            hv[j] = *(const ushort4*)(Hb + (size_t)(p[j] >> 15) * D + l * 4);
        #pragma unroll
        for (int j = 0; j < 8; ++j) {
            float w = __uint_as_float((p[j] & 0x7fffu) << 16);
            acc[0] = fmaf(w, bf2f(hv[j].x), acc[0]);
            acc[1] = fmaf(w, bf2f(hv[j].y), acc[1]);
            acc[2] = fmaf(w, bf2f(hv[j].z), acc[2]);
            acc[3] = fmaf(w, bf2f(hv[j].w), acc[3]);
        }
    }
    for (; e < end; ++e) {
        unsigned p0 = swp[e];
        ushort4 h0 = *(const ushort4*)(Hb + (size_t)(p0 >> 15) * D + l * 4);
        float w = __uint_as_float((p0 & 0x7fffu) << 16);
        acc[0] = fmaf(w, bf2f(h0.x), acc[0]);
        acc[1] = fmaf(w, bf2f(h0.y), acc[1]);
        acc[2] = fmaf(w, bf2f(h0.z), acc[2]);
        acc[3] = fmaf(w, bf2f(h0.w), acc[3]);
    }
    size_t o4 = (size_t)node * 32 + l;
    f32x4 bv = ((const f32x4*)bias)[l];
    f32x4 mv = __builtin_nontemporal_load((const f32x4*)mask + o4);
    u32x2 lv = __builtin_nontemporal_load((const u32x2*)lnb + o4);
    f32x4 r;
    r[0] = (acc[0] + bv[0]) * mv[0] - bf2f((unsigned short)(lv[0] & 0xffffu));
    r[1] = (acc[1] + bv[1]) * mv[1] - bf2f((unsigned short)(lv[0] >> 16));
    r[2] = (acc[2] + bv[2]) * mv[2] - bf2f((unsigned short)(lv[1] & 0xffffu));
    r[3] = (acc[3] + bv[3]) * mv[3] - bf2f((unsigned short)(lv[1] >> 16));
    __builtin_nontemporal_store(r, (f32x4*)out + o4);
}

extern "C" void kernel_launch(void* const* d_in, const int* in_sizes, int n_in,
                              void* d_out, int out_size, void* d_ws, size_t ws_size,
                              hipStream_t stream) {
    const float* node_inputs = (const float*)d_in[0];
    const int*   edge_index  = (const int*)d_in[1];
    const float* edge_w      = (const float*)d_in[2];
    const float* W           = (const float*)d_in[3];
    const float* bias        = (const float*)d_in[4];
    const float* mask        = (const float*)d_in[5];
    float* out = (float*)d_out;

    const size_t ND = (size_t)N_NODES * D;
    unsigned short* lnb    = (unsigned short*)d_ws;                 // ND bf16 (12.8 MB)
    unsigned short* Hb     = lnb + ND;                              // ND bf16 (12.8 MB)
    int2*           bstage = (int2*)(Hb + ND);                      // NBKT*BCAP int2 (8.0 MB)
    unsigned*       swp    = (unsigned*)(bstage + (size_t)NBKT * BCAP);  // NBKT*BCAP u32 (4.0 MB)
    int2*           rowse  = (int2*)(swp + (size_t)NBKT * BCAP);    // N int2 (0.4 MB)
    unsigned short* Wt     = (unsigned short*)(rowse + N_NODES);    // 16384 bf16 (32 KB)
    int*            bcnt   = (int*)(Wt + 128 * 128);                // NBKT ints

    wprep_kernel<<<64, 256, 0, stream>>>(W, Wt, bcnt);
    lngemm_kernel<<<(N_NODES + 63) / 64, 256, 0, stream>>>(node_inputs, Wt, lnb, Hb);
    phase1_kernel<<<P1_BLOCKS, 256, 0, stream>>>(edge_index, edge_w, bcnt, bstage);
    phase2_kernel<<<NBKT, 256, 0, stream>>>(bstage, bcnt, rowse, swp);
    gather_kernel<<<N_NODES / 8, 256, 0, stream>>>(rowse, swp, Hb, bias, mask, lnb, out);
}

// Round 14
// 192.926 us; speedup vs baseline: 1.4043x; 1.0338x over previous
//
#include <hip/hip_runtime.h>

#define N_NODES 50000
#define D 128
#define E_EDGES 800000
#define EPS 1e-5f

#define BKT_SHIFT 8
#define BNODES 256                      // nodes per bucket
#define NBKT 196                        // ceil(50000/256)
#define BCAP 4608                       // slots per bucket (mean 4082, ~8 sigma pad)
#define P1_EPB 4096                     // edges per phase-1 block
#define P1_BLOCKS 196                   // ceil(800000/4096)

typedef __attribute__((ext_vector_type(8))) short bf16x8;
typedef __attribute__((ext_vector_type(4))) float f32x4;
typedef __attribute__((ext_vector_type(2))) unsigned u32x2;

static __device__ __forceinline__ unsigned short f2bf(float f) {
    unsigned u = __float_as_uint(f);
    u = (u + 0x7fffu + ((u >> 16) & 1u)) >> 16;   // RNE
    return (unsigned short)u;
}
static __device__ __forceinline__ float bf2f(unsigned short h) {
    return __uint_as_float((unsigned)h << 16);
}

// ---- Kernel 0: W -> Wt[col][k] bf16 (fragment-contiguous) + zero bucket counters --
__global__ __launch_bounds__(256) void wprep_kernel(const float* __restrict__ W,
                                                    unsigned short* __restrict__ Wt,
                                                    int* __restrict__ bcnt) {
    int idx = blockIdx.x * 256 + threadIdx.x;       // 64 blocks * 256 = 16384 exact
    if (blockIdx.x == 0 && threadIdx.x < NBKT) bcnt[threadIdx.x] = 0;
    int k = idx >> 7, c = idx & 127;
    Wt[c * 128 + k] = f2bf(W[idx]);
}

// ---- Kernel 1: fused LayerNorm (bf16 out) + H = LN @ W (bf16 MFMA, bf16 out) ----
// 256 thr = 4 waves, 64 rows. B-fragments: one 16B load each from Wt (L2-hot).
__global__ __launch_bounds__(256, 4) void lngemm_kernel(const float* __restrict__ x,
                                                        const unsigned short* __restrict__ Wt,
                                                        unsigned short* __restrict__ lnb,
                                                        unsigned short* __restrict__ Hb) {
    __shared__ __align__(16) unsigned char A_lds[64 * 256];   // 64 rows x 128 bf16, swizzled
    int tid  = threadIdx.x;
    int wv   = tid >> 6;
    int lane = tid & 63;
    int row0 = blockIdx.x * 64;

    // --- B fragments: wave owns col-tiles {2wv, 2wv+1}; 8 x dwordx4 loads total ---
    bf16x8 bfrag[2][4];
    #pragma unroll
    for (int ci = 0; ci < 2; ++ci) {
        int col = (wv * 2 + ci) * 16 + (lane & 15);
        #pragma unroll
        for (int kb = 0; kb < 4; ++kb)
            bfrag[ci][kb] = *(const bf16x8*)(Wt + col * 128 + kb * 32 + (lane >> 4) * 8);
    }

    // --- LN: prefetch all 16 rows (independent loads), then reduce ---
    float2 xv[16];
    #pragma unroll
    for (int i = 0; i < 16; ++i) {
        int row = row0 + wv * 16 + i;
        xv[i] = (row < N_NODES) ? ((const float2*)(x + (size_t)row * D))[lane]
                                : make_float2(0.f, 0.f);
    }
    #pragma unroll
    for (int i = 0; i < 16; ++i) {
        int lr  = wv * 16 + i;
        int row = row0 + lr;
        float2 v = xv[i];
        float s = v.x + v.y;
        #pragma unroll
        for (int off = 32; off > 0; off >>= 1) s += __shfl_xor(s, off);
        float mu = s * (1.0f / D);
        float dx = v.x - mu, dy = v.y - mu;
        float vs = dx * dx + dy * dy;
        #pragma unroll
        for (int off = 32; off > 0; off >>= 1) vs += __shfl_xor(vs, off);
        float rstd = rsqrtf(vs * (1.0f / D) + EPS);
        unsigned pk = (unsigned)f2bf(dx * rstd) | ((unsigned)f2bf(dy * rstd) << 16);
        if (row < N_NODES) ((unsigned*)lnb)[(size_t)row * 64 + lane] = pk;
        *(unsigned*)(A_lds + lr * 256 + ((4 * lane) ^ ((i & 7) << 4))) = pk;  // pad rows: zeros
    }
    __syncthreads();

    // --- MFMA: 4 row-tiles x 2 col-tiles x 4 k-blocks per wave ---
    f32x4 acc[4][2] = {};
    #pragma unroll
    for (int kb = 0; kb < 4; ++kb) {
        #pragma unroll
        for (int rt = 0; rt < 4; ++rt) {
            int lr = rt * 16 + (lane & 15);
            bf16x8 af = *(const bf16x8*)(A_lds + lr * 256 +
                          ((kb * 64 + (lane >> 4) * 16) ^ ((lr & 7) << 4)));
            acc[rt][0] = __builtin_amdgcn_mfma_f32_16x16x32_bf16(af, bfrag[0][kb], acc[rt][0], 0, 0, 0);
            acc[rt][1] = __builtin_amdgcn_mfma_f32_16x16x32_bf16(af, bfrag[1][kb], acc[rt][1], 0, 0, 0);
        }
    }

    // --- epilogue: H bf16.  C/D layout: col = lane&15, row = (lane>>4)*4 + reg ---
    #pragma unroll
    for (int rt = 0; rt < 4; ++rt) {
        #pragma unroll
        for (int ci = 0; ci < 2; ++ci) {
            int col   = (wv * 2 + ci) * 16 + (lane & 15);
            int rbase = row0 + rt * 16 + ((lane >> 4) << 2);
            #pragma unroll
            for (int reg = 0; reg < 4; ++reg) {
                int r = rbase + reg;
                if (r < N_NODES)
                    Hb[(size_t)r * D + col] = f2bf(acc[rt][ci][reg]);
            }
        }
    }
}

// ---- Kernel 2: phase-1 partition into static bucket regions -----------------
__global__ __launch_bounds__(256) void phase1_kernel(const int* __restrict__ ei,
                                                     const float* __restrict__ ew,
                                                     int* __restrict__ bcnt,
                                                     int2* __restrict__ bstage) {
    __shared__ int h[NBKT], grun[NBKT], lcur[NBKT];
    int t = threadIdx.x;
    int base = blockIdx.x * P1_EPB;
    for (int i = t; i < NBKT; i += 256) h[i] = 0;
    __syncthreads();
    int cnt = E_EDGES - base; if (cnt > P1_EPB) cnt = P1_EPB;
    for (int i = t; i < cnt; i += 256)
        atomicAdd(&h[ei[E_EDGES + base + i] >> BKT_SHIFT], 1);
    __syncthreads();
    if (t < NBKT) {
        grun[t] = h[t] ? atomicAdd(&bcnt[t], h[t]) : 0;
        lcur[t] = 0;
    }
    __syncthreads();
    for (int i = t; i < cnt; i += 256) {
        int e   = base + i;
        int dst = ei[E_EDGES + e];
        int bkt = dst >> BKT_SHIFT;
        int r   = atomicAdd(&lcur[bkt], 1);
        int2 p;
        p.x = dst;
        p.y = (int)(((unsigned)ei[e] << 15) | ((unsigned)f2bf(ew[e]) & 0x7fffu));
        bstage[(size_t)bkt * BCAP + grun[bkt] + r] = p;
    }
}

// ---- Kernel 3: phase-2 per-bucket counting sort -> swp + per-node (beg,end) -----
// One block per 256-node bucket (196 blocks).
__global__ __launch_bounds__(256) void phase2_kernel(const int2* __restrict__ bstage,
                                                     const int* __restrict__ bcnt,
                                                     int2* __restrict__ rowse,
                                                     unsigned* __restrict__ swp) {
    __shared__ int cnt[BNODES], ncur[BNODES];
    int b = blockIdx.x, t = threadIdx.x;
    int nbase = b << BKT_SHIFT;
    int ebase = b * BCAP;
    int ecnt  = bcnt[b];
    cnt[t] = 0;
    __syncthreads();
    for (int i = t; i < ecnt; i += 256)
        atomicAdd(&cnt[bstage[ebase + i].x - nbase], 1);
    __syncthreads();
    int my = cnt[t];
    __syncthreads();
    // inclusive Hillis-Steele over 256, 1 elem/thread
    #pragma unroll
    for (int off = 1; off < BNODES; off <<= 1) {
        int u = (t >= off) ? cnt[t - off] : 0;
        __syncthreads();
        cnt[t] += u;
        __syncthreads();
    }
    int beg  = ebase + cnt[t] - my;
    int node = nbase + t;
    ncur[t] = beg;
    if (node < N_NODES) rowse[node] = make_int2(beg, ebase + cnt[t]);
    __syncthreads();
    for (int i = t; i < ecnt; i += 256) {
        int2 p = bstage[ebase + i];
        int pos = atomicAdd(&ncur[p.x - nbase], 1);
        swp[pos] = (unsigned)p.y;
    }
}

// ---- Kernel 4: gather-aggregate (bf16 H) + fused bias/dropout/residual ----------
// Half-wave (32 lanes) per node; nontemporal on all streamed traffic.
__global__ __launch_bounds__(256) void gather_kernel(const int2* __restrict__ rowse,
                                                     const unsigned* __restrict__ swp,
                                                     const unsigned short* __restrict__ Hb,
                                                     const float* __restrict__ bias,
                                                     const float* __restrict__ mask,
                                                     const unsigned short* __restrict__ lnb,
                                                     float* __restrict__ out) {
    int wave = threadIdx.x >> 6;
    int lane = threadIdx.x & 63;
    int half = lane >> 5;
    int l    = lane & 31;
    int node = blockIdx.x * 8 + wave * 2 + half;   // 6250 * 8 = 50000 exact
    int2 se  = rowse[node];
    int e = se.x, end = se.y;
    f32x4 acc = {0.f, 0.f, 0.f, 0.f};
    for (; e + 8 <= end; e += 8) {                 // 8-edge MLP
        unsigned p[8]; ushort4 hv[8];
        #pragma unroll
        for (int j = 0; j < 8; ++j) p[j] = __builtin_nontemporal_load(swp + e + j);
        #pragma unroll
        for (int j = 0; j < 8; ++j)
            hv[j] = *(const ushort4*)(Hb + (size_t)(p[j] >> 15) * D + l * 4);
        #pragma unroll
        for (int j = 0; j < 8; ++j) {
            float w = __uint_as_float((p[j] & 0x7fffu) << 16);
            acc[0] = fmaf(w, bf2f(hv[j].x), acc[0]);
            acc[1] = fmaf(w, bf2f(hv[j].y), acc[1]);
            acc[2] = fmaf(w, bf2f(hv[j].z), acc[2]);
            acc[3] = fmaf(w, bf2f(hv[j].w), acc[3]);
        }
    }
    for (; e < end; ++e) {
        unsigned p0 = swp[e];
        ushort4 h0 = *(const ushort4*)(Hb + (size_t)(p0 >> 15) * D + l * 4);
        float w = __uint_as_float((p0 & 0x7fffu) << 16);
        acc[0] = fmaf(w, bf2f(h0.x), acc[0]);
        acc[1] = fmaf(w, bf2f(h0.y), acc[1]);
        acc[2] = fmaf(w, bf2f(h0.z), acc[2]);
        acc[3] = fmaf(w, bf2f(h0.w), acc[3]);
    }
    size_t o4 = (size_t)node * 32 + l;
    f32x4 bv = ((const f32x4*)bias)[l];
    f32x4 mv = __builtin_nontemporal_load((const f32x4*)mask + o4);
    u32x2 lv = __builtin_nontemporal_load((const u32x2*)lnb + o4);
    f32x4 r;
    r[0] = (acc[0] + bv[0]) * mv[0] - bf2f((unsigned short)(lv[0] & 0xffffu));
    r[1] = (acc[1] + bv[1]) * mv[1] - bf2f((unsigned short)(lv[0] >> 16));
    r[2] = (acc[2] + bv[2]) * mv[2] - bf2f((unsigned short)(lv[1] & 0xffffu));
    r[3] = (acc[3] + bv[3]) * mv[3] - bf2f((unsigned short)(lv[1] >> 16));
    __builtin_nontemporal_store(r, (f32x4*)out + o4);
}

extern "C" void kernel_launch(void* const* d_in, const int* in_sizes, int n_in,
                              void* d_out, int out_size, void* d_ws, size_t ws_size,
                              hipStream_t stream) {
    const float* node_inputs = (const float*)d_in[0];
    const int*   edge_index  = (const int*)d_in[1];
    const float* edge_w      = (const float*)d_in[2];
    const float* W           = (const float*)d_in[3];
    const float* bias        = (const float*)d_in[4];
    const float* mask        = (const float*)d_in[5];
    float* out = (float*)d_out;

    const size_t ND = (size_t)N_NODES * D;
    const size_t NSLOT = (size_t)NBKT * BCAP;                      // 903168
    unsigned short* lnb    = (unsigned short*)d_ws;                 // ND bf16 (12.8 MB)
    unsigned short* Hb     = lnb + ND;                              // ND bf16 (12.8 MB)
    int2*           bstage = (int2*)(Hb + ND);                      // NSLOT int2 (7.2 MB)
    unsigned*       swp    = (unsigned*)(bstage + NSLOT);           // NSLOT u32 (3.6 MB)
    int2*           rowse  = (int2*)(swp + NSLOT);                  // N int2 (0.4 MB)
    unsigned short* Wt     = (unsigned short*)(rowse + N_NODES);    // 16384 bf16 (32 KB)
    int*            bcnt   = (int*)(Wt + 128 * 128);                // NBKT ints

    wprep_kernel<<<64, 256, 0, stream>>>(W, Wt, bcnt);
    lngemm_kernel<<<(N_NODES + 63) / 64, 256, 0, stream>>>(node_inputs, Wt, lnb, Hb);
    phase1_kernel<<<P1_BLOCKS, 256, 0, stream>>>(edge_index, edge_w, bcnt, bstage);
    phase2_kernel<<<NBKT, 256, 0, stream>>>(bstage, bcnt, rowse, swp);
    gather_kernel<<<N_NODES / 8, 256, 0, stream>>>(rowse, swp, Hb, bias, mask, lnb, out);
}